// Round 2
// baseline (584.719 us; speedup 1.0000x reference)
//
#include <hip/hip_runtime.h>
#include <hip/hip_bf16.h>
#include <cstdint>
#include <cstddef>

#define LSEQ 768
#define CS 384
#define CZ 128
#define NH 8
#define HD 48
#define LL (LSEQ*LSEQ)   /* 589824 */

static constexpr float EPS = 1e-5f;
static constexpr float QK_SCALE = 0.14433756729740643f; /* 1/sqrt(48) */

/* ---------------- 1. LayerNorm(single) -> s (fp32) ---------------- */
__global__ void k_ln_single(const float* __restrict__ single,
                            const float* __restrict__ g,
                            const float* __restrict__ b,
                            float* __restrict__ s_out){
  const int i = blockIdx.x;
  const int lane = threadIdx.x;
  const float* row = single + i*CS;
  float x[6];
  float sum = 0.f;
#pragma unroll
  for(int e=0;e<6;e++){ x[e] = row[lane + 64*e]; sum += x[e]; }
#pragma unroll
  for(int m=32;m>=1;m>>=1) sum += __shfl_xor(sum, m, 64);
  const float mu = sum * (1.f/CS);
  float vs = 0.f;
#pragma unroll
  for(int e=0;e<6;e++){ float d = x[e]-mu; vs += d*d; }
#pragma unroll
  for(int m=32;m>=1;m>>=1) vs += __shfl_xor(vs, m, 64);
  const float rs = rsqrtf(vs*(1.f/CS) + EPS);
#pragma unroll
  for(int e=0;e<6;e++){
    int c = lane + 64*e;
    s_out[i*CS + c] = (x[e]-mu)*rs*g[c] + b[c];
  }
}

/* ------- 2. fused LayerNorm(pair) + bias projection z@Wb -> bias[h][i][j] ------- */
/* 16 lanes per (i,j) row (8 z each), 4 rows per wave, 16 rows per block-iter. */
__global__ __launch_bounds__(256,4) void k_pair_bias(
    const float* __restrict__ pair,
    const float* __restrict__ g_z,
    const float* __restrict__ b_z,
    const float* __restrict__ Wb,
    float* __restrict__ bias){
  const int t = threadIdx.x;
  const int lane = t & 63;
  const int wave = t >> 6;
  const int sub  = lane >> 4;   /* row within wave's group of 4 */
  const int lg   = lane & 15;   /* lane within 16-lane row group */
  const int z0   = lg*8;

  float wb_r[64], gz[8], bz[8];
#pragma unroll
  for(int zz=0; zz<8; zz++){
    gz[zz] = g_z[z0+zz];
    bz[zz] = b_z[z0+zz];
#pragma unroll
    for(int h=0; h<NH; h++) wb_r[zz*8+h] = Wb[(z0+zz)*NH + h];
  }

  const int ngroups = LL/16;  /* 36864 */
  for(int gidx = blockIdx.x; gidx < ngroups; gidx += gridDim.x){
    const int r = gidx*16 + wave*4 + sub;   /* flattened i*768 + j */
    const float4 u0 = *(const float4*)(pair + (size_t)r*CZ + z0);
    const float4 u1 = *(const float4*)(pair + (size_t)r*CZ + z0 + 4);
    float x[8] = {u0.x,u0.y,u0.z,u0.w,u1.x,u1.y,u1.z,u1.w};
    float sum=0.f, sq=0.f;
#pragma unroll
    for(int e=0;e<8;e++){ sum += x[e]; sq += x[e]*x[e]; }
#pragma unroll
    for(int m=1;m<16;m<<=1){ sum += __shfl_xor(sum,m,64); sq += __shfl_xor(sq,m,64); }
    const float mu = sum*(1.f/CZ);
    const float rs = rsqrtf(sq*(1.f/CZ) - mu*mu + EPS);
    float zn[8];
#pragma unroll
    for(int e=0;e<8;e++) zn[e] = (x[e]-mu)*rs*gz[e] + bz[e];
    float acc[8];
#pragma unroll
    for(int h=0;h<8;h++){
      float a = 0.f;
#pragma unroll
      for(int e=0;e<8;e++) a += zn[e]*wb_r[e*8+h];
      acc[h]=a;
    }
#pragma unroll
    for(int h=0;h<8;h++){
#pragma unroll
      for(int m=1;m<16;m<<=1) acc[h] += __shfl_xor(acc[h],m,64);
    }
    float outv = acc[0];
#pragma unroll
    for(int h=1;h<8;h++) if(lg==h) outv = acc[h];
    if(lg < 8) bias[(size_t)lg*LL + r] = outv;
  }
}

/* ---------------- 3. s @ {Wq,Wk,Wv,Wg}^T  (fp32 tiled GEMM) ---------------- */
__global__ __launch_bounds__(256) void k_qkvg(
    const float* __restrict__ s,
    const float* __restrict__ Wq, const float* __restrict__ Wk,
    const float* __restrict__ Wv, const float* __restrict__ Wg,
    const float* __restrict__ bg,
    float* __restrict__ q, float* __restrict__ k,
    float* __restrict__ v, float* __restrict__ gate){
  const int which = blockIdx.z;
  const float* W = (which==0)?Wq : (which==1)?Wk : (which==2)?Wv : Wg;
  float* out = (which==0)?q : (which==1)?k : (which==2)?v : gate;
  __shared__ float As[16][65];
  __shared__ float Bs[16][65];
  const int t = threadIdx.x;
  const int m0 = blockIdx.x*64;
  const int n0 = blockIdx.y*64;
  const int tx = t & 15, ty = t >> 4;
  float acc[4][4] = {};
  for(int k0=0;k0<CS;k0+=16){
#pragma unroll
    for(int e=0;e<4;e++){
      int idx = t + e*256;
      int kk = idx & 15, mm = idx >> 4;
      As[kk][mm] = s[(m0+mm)*CS + k0 + kk];
      Bs[kk][mm] = W[(n0+mm)*CS + k0 + kk];
    }
    __syncthreads();
#pragma unroll
    for(int kk=0;kk<16;kk++){
      float a[4], bb[4];
#pragma unroll
      for(int rr=0;rr<4;rr++) a[rr]=As[kk][ty+16*rr];
#pragma unroll
      for(int cc=0;cc<4;cc++) bb[cc]=Bs[kk][tx+16*cc];
#pragma unroll
      for(int rr=0;rr<4;rr++)
#pragma unroll
        for(int cc=0;cc<4;cc++) acc[rr][cc] += a[rr]*bb[cc];
    }
    __syncthreads();
  }
#pragma unroll
  for(int rr=0;rr<4;rr++){
    int m = m0 + ty + 16*rr;
#pragma unroll
    for(int cc=0;cc<4;cc++){
      int n = n0 + tx + 16*cc;
      float val = acc[rr][cc];
      if(which==3) val = 1.f/(1.f + __expf(-(val + bg[n])));
      out[m*CS+n] = val;
    }
  }
}

/* ---------------- 4. logits[h,i,j] = qk*scale + bias (in-place) ---------------- */
__global__ __launch_bounds__(256) void k_qk(
    const float* __restrict__ q, const float* __restrict__ k,
    float* __restrict__ logits){
  const int h  = blockIdx.z;
  const int i0 = blockIdx.y*32;
  const int j0 = blockIdx.x*64;
  __shared__ float Qs[32][49];
  __shared__ float Ks[64][49];
  const int t = threadIdx.x;
#pragma unroll
  for(int e=0;e<6;e++){
    int idx = t + e*256;
    int d = idx % 48, ii = idx / 48;
    Qs[ii][d] = q[(i0+ii)*CS + h*HD + d];
  }
#pragma unroll
  for(int e=0;e<12;e++){
    int idx = t + e*256;
    int d = idx % 48, jj = idx / 48;
    Ks[jj][d] = k[(j0+jj)*CS + h*HD + d];
  }
  __syncthreads();
  const int tx = t & 15, ty = t >> 4;
  float acc[2][4] = {};
#pragma unroll
  for(int d=0; d<HD; d++){
    float a0 = Qs[ty][d],    a1 = Qs[ty+16][d];
    float b0 = Ks[tx][d],    b1 = Ks[tx+16][d];
    float b2 = Ks[tx+32][d], b3 = Ks[tx+48][d];
    acc[0][0]+=a0*b0; acc[0][1]+=a0*b1; acc[0][2]+=a0*b2; acc[0][3]+=a0*b3;
    acc[1][0]+=a1*b0; acc[1][1]+=a1*b1; acc[1][2]+=a1*b2; acc[1][3]+=a1*b3;
  }
#pragma unroll
  for(int ri=0;ri<2;ri++){
    int i = i0 + ty + 16*ri;
#pragma unroll
    for(int cj=0;cj<4;cj++){
      int j = j0 + tx + 16*cj;
      size_t idx = (size_t)h*LL + (size_t)i*LSEQ + j;
      logits[idx] = acc[ri][cj]*QK_SCALE + logits[idx];
    }
  }
}

/* ---------------- 5. softmax over j, in place ---------------- */
__global__ __launch_bounds__(256) void k_softmax(float* __restrict__ logits){
  const int row = blockIdx.x; /* h*768 + i */
  float* p = logits + (size_t)row*LSEQ;
  const int t = threadIdx.x;
  __shared__ float red[4];
  const int wave = t >> 6, lane = t & 63;
  float x[3];
  float mx = -1e30f;
#pragma unroll
  for(int e=0;e<3;e++){ x[e] = p[t + e*256]; mx = fmaxf(mx, x[e]); }
#pragma unroll
  for(int m=32;m>=1;m>>=1) mx = fmaxf(mx, __shfl_xor(mx,m,64));
  if(lane==0) red[wave]=mx;
  __syncthreads();
  mx = fmaxf(fmaxf(red[0],red[1]), fmaxf(red[2],red[3]));
  __syncthreads();
  float sum = 0.f;
#pragma unroll
  for(int e=0;e<3;e++){ x[e] = __expf(x[e]-mx); sum += x[e]; }
#pragma unroll
  for(int m=32;m>=1;m>>=1) sum += __shfl_xor(sum,m,64);
  if(lane==0) red[wave]=sum;
  __syncthreads();
  sum = red[0]+red[1]+red[2]+red[3];
  const float inv = 1.f/sum;
#pragma unroll
  for(int e=0;e<3;e++) p[t+e*256] = x[e]*inv;
}

/* ---------------- 6. attno[i, h*48+d] = sum_j P[h,i,j] * v[j,h*48+d] ---------------- */
__global__ __launch_bounds__(256) void k_pv(
    const float* __restrict__ P, const float* __restrict__ v,
    float* __restrict__ attno){
  const int h  = blockIdx.y;
  const int i0 = blockIdx.x*64;
  __shared__ float Ps[64][65];
  __shared__ float Vs[64][49];
  const int t = threadIdx.x;
  const int tx = t & 15, ty = t >> 4;
  float acc[4][3] = {};
  for(int j0=0;j0<LSEQ;j0+=64){
#pragma unroll
    for(int e=0;e<16;e++){
      int idx = t + e*256;
      int jj = idx & 63, ii = idx >> 6;
      Ps[ii][jj] = P[(size_t)h*LL + (size_t)(i0+ii)*LSEQ + j0 + jj];
    }
#pragma unroll
    for(int e=0;e<12;e++){
      int idx = t + e*256;
      int d = idx % 48, jj = idx / 48;
      Vs[jj][d] = v[(j0+jj)*CS + h*HD + d];
    }
    __syncthreads();
#pragma unroll
    for(int jj=0;jj<64;jj++){
      float b0 = Vs[jj][tx], b1 = Vs[jj][tx+16], b2 = Vs[jj][tx+32];
      float a[4];
#pragma unroll
      for(int ri=0;ri<4;ri++) a[ri] = Ps[ty+16*ri][jj];
#pragma unroll
      for(int ri=0;ri<4;ri++){
        acc[ri][0]+=a[ri]*b0; acc[ri][1]+=a[ri]*b1; acc[ri][2]+=a[ri]*b2;
      }
    }
    __syncthreads();
  }
#pragma unroll
  for(int ri=0;ri<4;ri++){
    int i = i0 + ty + 16*ri;
#pragma unroll
    for(int c=0;c<3;c++)
      attno[i*CS + h*HD + tx + 16*c] = acc[ri][c];
  }
}

/* ------- 7. out = single + gate * (attno @ Wo^T + bo), fp32 store ------- */
__global__ __launch_bounds__(256) void k_final(
    const float* __restrict__ attno, const float* __restrict__ Wo,
    const float* __restrict__ bo, const float* __restrict__ single,
    const float* __restrict__ gate, float* __restrict__ out){
  __shared__ float As[16][65];
  __shared__ float Bs[16][65];
  const int t = threadIdx.x;
  const int m0 = blockIdx.x*64;
  const int n0 = blockIdx.y*64;
  const int tx = t & 15, ty = t >> 4;
  float acc[4][4] = {};
  for(int k0=0;k0<CS;k0+=16){
#pragma unroll
    for(int e=0;e<4;e++){
      int idx = t + e*256;
      int kk = idx & 15, mm = idx >> 4;
      As[kk][mm] = attno[(m0+mm)*CS + k0 + kk];
      Bs[kk][mm] = Wo[(n0+mm)*CS + k0 + kk];
    }
    __syncthreads();
#pragma unroll
    for(int kk=0;kk<16;kk++){
      float a[4], bb[4];
#pragma unroll
      for(int rr=0;rr<4;rr++) a[rr]=As[kk][ty+16*rr];
#pragma unroll
      for(int cc=0;cc<4;cc++) bb[cc]=Bs[kk][tx+16*cc];
#pragma unroll
      for(int rr=0;rr<4;rr++)
#pragma unroll
        for(int cc=0;cc<4;cc++) acc[rr][cc] += a[rr]*bb[cc];
    }
    __syncthreads();
  }
#pragma unroll
  for(int rr=0;rr<4;rr++){
    int m = m0 + ty + 16*rr;
#pragma unroll
    for(int cc=0;cc<4;cc++){
      int n = n0 + tx + 16*cc;
      float val = acc[rr][cc] + bo[n];
      out[m*CS+n] = single[m*CS+n] + gate[m*CS+n]*val;
    }
  }
}

extern "C" void kernel_launch(void* const* d_in, const int* in_sizes, int n_in,
                              void* d_out, int out_size, void* d_ws, size_t ws_size,
                              hipStream_t stream){
  (void)in_sizes; (void)n_in; (void)out_size; (void)ws_size;
  const float* single = (const float*)d_in[0];
  const float* pair   = (const float*)d_in[1];
  const float* g_s    = (const float*)d_in[2];
  const float* b_s    = (const float*)d_in[3];
  const float* g_z    = (const float*)d_in[4];
  const float* b_z    = (const float*)d_in[5];
  const float* Wq     = (const float*)d_in[6];
  const float* Wk     = (const float*)d_in[7];
  const float* Wv     = (const float*)d_in[8];
  const float* Wb     = (const float*)d_in[9];
  const float* Wo     = (const float*)d_in[10];
  const float* bo     = (const float*)d_in[11];
  const float* Wg     = (const float*)d_in[12];
  const float* bg     = (const float*)d_in[13];
  float* out = (float*)d_out;

  float* ws     = (float*)d_ws;
  float* logits = ws;                      /* [8][768][768] = 4718592 f32 */
  float* s      = ws + 4718592;            /* [768][384] */
  float* q      = s  + 294912;
  float* k      = q  + 294912;
  float* v      = k  + 294912;
  float* gate   = v  + 294912;
  float* attno  = gate + 294912;           /* end: 6488064 f32 = 25.95 MB */

  hipLaunchKernelGGL(k_ln_single, dim3(768),      dim3(64),  0, stream, single, g_s, b_s, s);
  hipLaunchKernelGGL(k_pair_bias, dim3(3072),     dim3(256), 0, stream, pair, g_z, b_z, Wb, logits);
  hipLaunchKernelGGL(k_qkvg,      dim3(12,6,4),   dim3(256), 0, stream, s, Wq, Wk, Wv, Wg, bg, q, k, v, gate);
  hipLaunchKernelGGL(k_qk,        dim3(12,24,8),  dim3(256), 0, stream, q, k, logits);
  hipLaunchKernelGGL(k_softmax,   dim3(6144),     dim3(256), 0, stream, logits);
  hipLaunchKernelGGL(k_pv,        dim3(12,8),     dim3(256), 0, stream, logits, v, attno);
  hipLaunchKernelGGL(k_final,     dim3(12,6),     dim3(256), 0, stream, attno, Wo, bo, single, gate, out);
}

// Round 3
// 528.396 us; speedup vs baseline: 1.1066x; 1.1066x over previous
//
#include <hip/hip_runtime.h>
#include <hip/hip_bf16.h>
#include <cstdint>
#include <cstddef>

#define LSEQ 768
#define CS 384
#define CZ 128
#define NH 8
#define HD 48
#define LL (LSEQ*LSEQ)   /* 589824 */

static constexpr float EPS = 1e-5f;
static constexpr float QK_SCALE = 0.14433756729740643f; /* 1/sqrt(48) */

typedef __attribute__((ext_vector_type(8))) short bf16x8;
typedef __attribute__((ext_vector_type(4))) float f32x4;

__device__ __forceinline__ short f2bf_s(float f){
  unsigned int u = __float_as_uint(f);
  unsigned int r = u + 0x7fffu + ((u >> 16) & 1u);  /* RNE */
  return (short)(r >> 16);
}

/* ---------------- 1. LayerNorm(single) -> s (fp32) ---------------- */
__global__ void k_ln_single(const float* __restrict__ single,
                            const float* __restrict__ g,
                            const float* __restrict__ b,
                            float* __restrict__ s_out){
  const int i = blockIdx.x;
  const int lane = threadIdx.x;
  const float* row = single + i*CS;
  float x[6];
  float sum = 0.f;
#pragma unroll
  for(int e=0;e<6;e++){ x[e] = row[lane + 64*e]; sum += x[e]; }
#pragma unroll
  for(int m=32;m>=1;m>>=1) sum += __shfl_xor(sum, m, 64);
  const float mu = sum * (1.f/CS);
  float vs = 0.f;
#pragma unroll
  for(int e=0;e<6;e++){ float d = x[e]-mu; vs += d*d; }
#pragma unroll
  for(int m=32;m>=1;m>>=1) vs += __shfl_xor(vs, m, 64);
  const float rs = rsqrtf(vs*(1.f/CS) + EPS);
#pragma unroll
  for(int e=0;e<6;e++){
    int c = lane + 64*e;
    s_out[i*CS + c] = (x[e]-mu)*rs*g[c] + b[c];
  }
}

/* ------- 2. fused LayerNorm(pair) + z@Wb -> bias[h][i][j] -------
   16 lanes per (i,j) row (8 z each). Reduction of 8 head-accums over 16
   lanes via component-splitting butterfly: 8 shuffles instead of 32. */
__global__ __launch_bounds__(256,4) void k_pair_bias(
    const float* __restrict__ pair,
    const float* __restrict__ g_z,
    const float* __restrict__ b_z,
    const float* __restrict__ Wb,
    float* __restrict__ bias){
  const int t = threadIdx.x;
  const int lane = t & 63;
  const int wave = t >> 6;
  const int sub  = lane >> 4;
  const int lg   = lane & 15;
  const int z0   = lg*8;

  float wb_r[64], gz[8], bz[8];
#pragma unroll
  for(int zz=0; zz<8; zz++){
    gz[zz] = g_z[z0+zz];
    bz[zz] = b_z[z0+zz];
#pragma unroll
    for(int h=0; h<NH; h++) wb_r[zz*8+h] = Wb[(z0+zz)*NH + h];
  }
  const int hmap = 4*(lg&1) + (lg&2) + ((lg>>2)&1);

  const int ngroups = LL/16;
  for(int gidx = blockIdx.x; gidx < ngroups; gidx += gridDim.x){
    const int r = gidx*16 + wave*4 + sub;
    const float4 u0 = *(const float4*)(pair + (size_t)r*CZ + z0);
    const float4 u1 = *(const float4*)(pair + (size_t)r*CZ + z0 + 4);
    float x[8] = {u0.x,u0.y,u0.z,u0.w,u1.x,u1.y,u1.z,u1.w};
    float sum=0.f, sq=0.f;
#pragma unroll
    for(int e=0;e<8;e++){ sum += x[e]; sq += x[e]*x[e]; }
#pragma unroll
    for(int m=1;m<16;m<<=1){ sum += __shfl_xor(sum,m,64); sq += __shfl_xor(sq,m,64); }
    const float mu = sum*(1.f/CZ);
    const float rs = rsqrtf(sq*(1.f/CZ) - mu*mu + EPS);
    float acc[8];
#pragma unroll
    for(int h=0;h<8;h++) acc[h]=0.f;
#pragma unroll
    for(int e=0;e<8;e++){
      const float zn = (x[e]-mu)*rs*gz[e] + bz[e];
#pragma unroll
      for(int h=0;h<8;h++) acc[h] += zn*wb_r[e*8+h];
    }
    /* butterfly with component splitting */
    float k1[4];
    {
      const bool hi = lg & 1;
#pragma unroll
      for(int j=0;j<4;j++){
        float send = hi ? acc[j] : acc[j+4];
        float recv = __shfl_xor(send, 1, 64);
        k1[j] = (hi ? acc[j+4] : acc[j]) + recv;
      }
    }
    float k2[2];
    {
      const bool hi = lg & 2;
#pragma unroll
      for(int j=0;j<2;j++){
        float send = hi ? k1[j] : k1[j+2];
        float recv = __shfl_xor(send, 2, 64);
        k2[j] = (hi ? k1[j+2] : k1[j]) + recv;
      }
    }
    float k3;
    {
      const bool hi = lg & 4;
      float send = hi ? k2[0] : k2[1];
      float recv = __shfl_xor(send, 4, 64);
      k3 = (hi ? k2[1] : k2[0]) + recv;
    }
    k3 += __shfl_xor(k3, 8, 64);
    if(lg < 8) bias[(size_t)hmap*LL + r] = k3;
  }
}

/* ---------------- 3. s @ {Wq,Wk,Wv,Wg}^T  (fp32 tiled GEMM) ---------------- */
__global__ __launch_bounds__(256) void k_qkvg(
    const float* __restrict__ s,
    const float* __restrict__ Wq, const float* __restrict__ Wk,
    const float* __restrict__ Wv, const float* __restrict__ Wg,
    const float* __restrict__ bg,
    float* __restrict__ q, float* __restrict__ k,
    float* __restrict__ v, float* __restrict__ gate){
  const int which = blockIdx.z;
  const float* W = (which==0)?Wq : (which==1)?Wk : (which==2)?Wv : Wg;
  float* out = (which==0)?q : (which==1)?k : (which==2)?v : gate;
  __shared__ float As[16][65];
  __shared__ float Bs[16][65];
  const int t = threadIdx.x;
  const int m0 = blockIdx.x*64;
  const int n0 = blockIdx.y*64;
  const int tx = t & 15, ty = t >> 4;
  float acc[4][4] = {};
  for(int k0=0;k0<CS;k0+=16){
#pragma unroll
    for(int e=0;e<4;e++){
      int idx = t + e*256;
      int kk = idx & 15, mm = idx >> 4;
      As[kk][mm] = s[(m0+mm)*CS + k0 + kk];
      Bs[kk][mm] = W[(n0+mm)*CS + k0 + kk];
    }
    __syncthreads();
#pragma unroll
    for(int kk=0;kk<16;kk++){
      float a[4], bb[4];
#pragma unroll
      for(int rr=0;rr<4;rr++) a[rr]=As[kk][ty+16*rr];
#pragma unroll
      for(int cc=0;cc<4;cc++) bb[cc]=Bs[kk][tx+16*cc];
#pragma unroll
      for(int rr=0;rr<4;rr++)
#pragma unroll
        for(int cc=0;cc<4;cc++) acc[rr][cc] += a[rr]*bb[cc];
    }
    __syncthreads();
  }
#pragma unroll
  for(int rr=0;rr<4;rr++){
    int m = m0 + ty + 16*rr;
#pragma unroll
    for(int cc=0;cc<4;cc++){
      int n = n0 + tx + 16*cc;
      float val = acc[rr][cc];
      if(which==3) val = 1.f/(1.f + __expf(-(val + bg[n])));
      out[m*CS+n] = val;
    }
  }
}

/* ---------- 4. fused flash attention: S=QK^T*sc+bias, softmax, O=PV ----------
   Block: 256 thr = 4 waves. 16 q-rows (i0..i0+15), head h. Wave w handles
   j in [w*192, (w+1)*192) with online softmax; 4-way merge via LDS. */
__global__ __launch_bounds__(256) void k_flash(
    const float* __restrict__ q, const float* __restrict__ k,
    const float* __restrict__ v, const float* __restrict__ bias,
    float* __restrict__ attno){
  const int h  = blockIdx.y;
  const int i0 = blockIdx.x * 16;
  const int t  = threadIdx.x;
  const int w    = t >> 6;
  const int lane = t & 63;
  const int ln   = lane & 15;
  const int quad = lane >> 4;

  __shared__ float S_lds[4][16][34];
  __shared__ float O_lds[4][16][48];
  __shared__ float ml_lds[4][2][16];

  /* Q A-frags (QK_SCALE folded in): A[m=ln][k=quad*8+e] = Q[i0+m][k] */
  bf16x8 aq0, aq1;
  {
    const float* qrow = q + (size_t)(i0 + ln)*CS + h*HD;
#pragma unroll
    for(int e=0;e<8;e++) aq0[e] = f2bf_s(qrow[quad*8 + e] * QK_SCALE);
    if(quad < 2){
#pragma unroll
      for(int e=0;e<8;e++) aq1[e] = f2bf_s(qrow[32 + quad*8 + e] * QK_SCALE);
    } else {
#pragma unroll
      for(int e=0;e<8;e++) aq1[e] = 0;
    }
  }

  float m_r[4], l_r[4];
  f32x4 o[3];
#pragma unroll
  for(int r=0;r<4;r++){ m_r[r] = -INFINITY; l_r[r] = 0.f; }
#pragma unroll
  for(int db=0;db<3;db++) o[db] = (f32x4){0.f,0.f,0.f,0.f};

  for(int jt=0; jt<6; jt++){
    const int j0 = w*192 + jt*32;
    /* K B-frags: B[k=quad*8+e][n=ln] = K[j0+jb*16+n][k] */
    f32x4 s_f[2];
#pragma unroll
    for(int jb=0;jb<2;jb++){
      const float* krow = k + (size_t)(j0 + jb*16 + ln)*CS + h*HD;
      bf16x8 bk0, bk1;
#pragma unroll
      for(int e=0;e<8;e++) bk0[e] = f2bf_s(krow[quad*8 + e]);
      if(quad < 2){
#pragma unroll
        for(int e=0;e<8;e++) bk1[e] = f2bf_s(krow[32 + quad*8 + e]);
      } else {
#pragma unroll
        for(int e=0;e<8;e++) bk1[e] = 0;
      }
      f32x4 acc = (f32x4){0.f,0.f,0.f,0.f};
      acc = __builtin_amdgcn_mfma_f32_16x16x32_bf16(aq0, bk0, acc, 0,0,0);
      acc = __builtin_amdgcn_mfma_f32_16x16x32_bf16(aq1, bk1, acc, 0,0,0);
      s_f[jb] = acc;
    }
    /* + bias; C-layout: row=quad*4+r, col=j0+jb*16+ln */
    float sv[2][4];
#pragma unroll
    for(int jb=0;jb<2;jb++)
#pragma unroll
      for(int r=0;r<4;r++)
        sv[jb][r] = s_f[jb][r] +
          bias[(size_t)h*LL + (size_t)(i0 + quad*4 + r)*LSEQ + j0 + jb*16 + ln];
    /* online softmax */
    float tmax[4];
#pragma unroll
    for(int r=0;r<4;r++) tmax[r] = fmaxf(sv[0][r], sv[1][r]);
#pragma unroll
    for(int r=0;r<4;r++)
#pragma unroll
      for(int m=1;m<16;m<<=1) tmax[r] = fmaxf(tmax[r], __shfl_xor(tmax[r], m, 64));
    float alpha[4];
#pragma unroll
    for(int r=0;r<4;r++){
      const float mn = fmaxf(m_r[r], tmax[r]);
      alpha[r] = __expf(m_r[r] - mn);
      m_r[r] = mn;
    }
    float p[2][4], tsum[4];
#pragma unroll
    for(int r=0;r<4;r++){
      p[0][r] = __expf(sv[0][r] - m_r[r]);
      p[1][r] = __expf(sv[1][r] - m_r[r]);
      tsum[r] = p[0][r] + p[1][r];
    }
#pragma unroll
    for(int r=0;r<4;r++)
#pragma unroll
      for(int m=1;m<16;m<<=1) tsum[r] += __shfl_xor(tsum[r], m, 64);
#pragma unroll
    for(int r=0;r<4;r++) l_r[r] = l_r[r]*alpha[r] + tsum[r];
#pragma unroll
    for(int db=0;db<3;db++)
#pragma unroll
      for(int r=0;r<4;r++) o[db][r] *= alpha[r];
    /* P: C-layout -> LDS -> A-layout bf16 */
#pragma unroll
    for(int jb=0;jb<2;jb++)
#pragma unroll
      for(int r=0;r<4;r++) S_lds[w][quad*4+r][jb*16+ln] = p[jb][r];
    bf16x8 ap;
#pragma unroll
    for(int e=0;e<8;e++) ap[e] = f2bf_s(S_lds[w][ln][quad*8+e]);
    /* V B-frags: B[k=quad*8+jj][n=ln] = V[j0+k][db*16+n] */
#pragma unroll
    for(int db=0;db<3;db++){
      bf16x8 bv;
#pragma unroll
      for(int jj=0;jj<8;jj++)
        bv[jj] = f2bf_s(v[(size_t)(j0 + quad*8 + jj)*CS + h*HD + db*16 + ln]);
      o[db] = __builtin_amdgcn_mfma_f32_16x16x32_bf16(ap, bv, o[db], 0,0,0);
    }
  }

  /* merge the 4 j-quarters */
#pragma unroll
  for(int db=0;db<3;db++)
#pragma unroll
    for(int r=0;r<4;r++) O_lds[w][quad*4+r][db*16+ln] = o[db][r];
  if(ln == 0){
#pragma unroll
    for(int r=0;r<4;r++){
      ml_lds[w][0][quad*4+r] = m_r[r];
      ml_lds[w][1][quad*4+r] = l_r[r];
    }
  }
  __syncthreads();
#pragma unroll
  for(int e=0;e<3;e++){
    const int idx = t + e*256;
    const int row = idx / 48, d = idx % 48;
    float M = ml_lds[0][0][row];
#pragma unroll
    for(int ww=1;ww<4;ww++) M = fmaxf(M, ml_lds[ww][0][row]);
    float L = 0.f, O = 0.f;
#pragma unroll
    for(int ww=0;ww<4;ww++){
      const float f = __expf(ml_lds[ww][0][row] - M);
      L += ml_lds[ww][1][row] * f;
      O += O_lds[ww][row][d] * f;
    }
    attno[(size_t)(i0+row)*CS + h*HD + d] = O / L;
  }
}

/* ------- 5. out = single + gate * (attno @ Wo^T + bo), fp32 store ------- */
__global__ __launch_bounds__(256) void k_final(
    const float* __restrict__ attno, const float* __restrict__ Wo,
    const float* __restrict__ bo, const float* __restrict__ single,
    const float* __restrict__ gate, float* __restrict__ out){
  __shared__ float As[16][65];
  __shared__ float Bs[16][65];
  const int t = threadIdx.x;
  const int m0 = blockIdx.x*64;
  const int n0 = blockIdx.y*64;
  const int tx = t & 15, ty = t >> 4;
  float acc[4][4] = {};
  for(int k0=0;k0<CS;k0+=16){
#pragma unroll
    for(int e=0;e<4;e++){
      int idx = t + e*256;
      int kk = idx & 15, mm = idx >> 4;
      As[kk][mm] = attno[(m0+mm)*CS + k0 + kk];
      Bs[kk][mm] = Wo[(n0+mm)*CS + k0 + kk];
    }
    __syncthreads();
#pragma unroll
    for(int kk=0;kk<16;kk++){
      float a[4], bb[4];
#pragma unroll
      for(int rr=0;rr<4;rr++) a[rr]=As[kk][ty+16*rr];
#pragma unroll
      for(int cc=0;cc<4;cc++) bb[cc]=Bs[kk][tx+16*cc];
#pragma unroll
      for(int rr=0;rr<4;rr++)
#pragma unroll
        for(int cc=0;cc<4;cc++) acc[rr][cc] += a[rr]*bb[cc];
    }
    __syncthreads();
  }
#pragma unroll
  for(int rr=0;rr<4;rr++){
    int m = m0 + ty + 16*rr;
#pragma unroll
    for(int cc=0;cc<4;cc++){
      int n = n0 + tx + 16*cc;
      float val = acc[rr][cc] + bo[n];
      out[m*CS+n] = single[m*CS+n] + gate[m*CS+n]*val;
    }
  }
}

extern "C" void kernel_launch(void* const* d_in, const int* in_sizes, int n_in,
                              void* d_out, int out_size, void* d_ws, size_t ws_size,
                              hipStream_t stream){
  (void)in_sizes; (void)n_in; (void)out_size; (void)ws_size;
  const float* single = (const float*)d_in[0];
  const float* pair   = (const float*)d_in[1];
  const float* g_s    = (const float*)d_in[2];
  const float* b_s    = (const float*)d_in[3];
  const float* g_z    = (const float*)d_in[4];
  const float* b_z    = (const float*)d_in[5];
  const float* Wq     = (const float*)d_in[6];
  const float* Wk     = (const float*)d_in[7];
  const float* Wv     = (const float*)d_in[8];
  const float* Wb     = (const float*)d_in[9];
  const float* Wo     = (const float*)d_in[10];
  const float* bo     = (const float*)d_in[11];
  const float* Wg     = (const float*)d_in[12];
  const float* bg     = (const float*)d_in[13];
  float* out = (float*)d_out;

  float* ws     = (float*)d_ws;
  float* bias   = ws;                      /* [8][768][768] */
  float* s      = ws + 4718592;
  float* q      = s  + 294912;
  float* k      = q  + 294912;
  float* v      = k  + 294912;
  float* gate   = v  + 294912;
  float* attno  = gate + 294912;

  hipLaunchKernelGGL(k_ln_single, dim3(768),     dim3(64),  0, stream, single, g_s, b_s, s);
  hipLaunchKernelGGL(k_pair_bias, dim3(3072),    dim3(256), 0, stream, pair, g_z, b_z, Wb, bias);
  hipLaunchKernelGGL(k_qkvg,      dim3(12,6,4),  dim3(256), 0, stream, s, Wq, Wk, Wv, Wg, bg, q, k, v, gate);
  hipLaunchKernelGGL(k_flash,     dim3(48,8),    dim3(256), 0, stream, q, k, v, bias, attno);
  hipLaunchKernelGGL(k_final,     dim3(12,6),    dim3(256), 0, stream, attno, Wo, bo, single, gate, out);
}

// Round 4
// 520.425 us; speedup vs baseline: 1.1235x; 1.0153x over previous
//
#include <hip/hip_runtime.h>
#include <hip/hip_bf16.h>
#include <cstdint>
#include <cstddef>

#define LSEQ 768
#define CS 384
#define CZ 128
#define NH 8
#define HD 48
#define LL (LSEQ*LSEQ)   /* 589824 */

static constexpr float EPS = 1e-5f;
static constexpr float QK_SCALE = 0.14433756729740643f; /* 1/sqrt(48) */

typedef unsigned short u16;
typedef __attribute__((ext_vector_type(8))) short bf16x8;
typedef __attribute__((ext_vector_type(4))) float f32x4;

__device__ __forceinline__ u16 f2bf_s(float f){
  unsigned int u = __float_as_uint(f);
  unsigned int r = u + 0x7fffu + ((u >> 16) & 1u);  /* RNE */
  return (u16)(r >> 16);
}

/* ---------------- 1. LayerNorm(single) -> s (fp32) ---------------- */
__global__ void k_ln_single(const float* __restrict__ single,
                            const float* __restrict__ g,
                            const float* __restrict__ b,
                            float* __restrict__ s_out){
  const int i = blockIdx.x;
  const int lane = threadIdx.x;
  const float* row = single + i*CS;
  float x[6];
  float sum = 0.f;
#pragma unroll
  for(int e=0;e<6;e++){ x[e] = row[lane + 64*e]; sum += x[e]; }
#pragma unroll
  for(int m=32;m>=1;m>>=1) sum += __shfl_xor(sum, m, 64);
  const float mu = sum * (1.f/CS);
  float vs = 0.f;
#pragma unroll
  for(int e=0;e<6;e++){ float d = x[e]-mu; vs += d*d; }
#pragma unroll
  for(int m=32;m>=1;m>>=1) vs += __shfl_xor(vs, m, 64);
  const float rs = rsqrtf(vs*(1.f/CS) + EPS);
#pragma unroll
  for(int e=0;e<6;e++){
    int c = lane + 64*e;
    s_out[i*CS + c] = (x[e]-mu)*rs*g[c] + b[c];
  }
}

/* ------- 2. fused LayerNorm(pair) + z@Wb -> bias[h][i][j] ------- */
__global__ __launch_bounds__(256,4) void k_pair_bias(
    const float* __restrict__ pair,
    const float* __restrict__ g_z,
    const float* __restrict__ b_z,
    const float* __restrict__ Wb,
    float* __restrict__ bias){
  const int t = threadIdx.x;
  const int lane = t & 63;
  const int wave = t >> 6;
  const int sub  = lane >> 4;
  const int lg   = lane & 15;
  const int z0   = lg*8;

  float wb_r[64], gz[8], bz[8];
#pragma unroll
  for(int zz=0; zz<8; zz++){
    gz[zz] = g_z[z0+zz];
    bz[zz] = b_z[z0+zz];
#pragma unroll
    for(int h=0; h<NH; h++) wb_r[zz*8+h] = Wb[(z0+zz)*NH + h];
  }
  const int hmap = 4*(lg&1) + (lg&2) + ((lg>>2)&1);

  const int ngroups = LL/16;
  for(int gidx = blockIdx.x; gidx < ngroups; gidx += gridDim.x){
    const int r = gidx*16 + wave*4 + sub;
    const float4 u0 = *(const float4*)(pair + (size_t)r*CZ + z0);
    const float4 u1 = *(const float4*)(pair + (size_t)r*CZ + z0 + 4);
    float x[8] = {u0.x,u0.y,u0.z,u0.w,u1.x,u1.y,u1.z,u1.w};
    float sum=0.f, sq=0.f;
#pragma unroll
    for(int e=0;e<8;e++){ sum += x[e]; sq += x[e]*x[e]; }
#pragma unroll
    for(int m=1;m<16;m<<=1){ sum += __shfl_xor(sum,m,64); sq += __shfl_xor(sq,m,64); }
    const float mu = sum*(1.f/CZ);
    const float rs = rsqrtf(sq*(1.f/CZ) - mu*mu + EPS);
    float acc[8];
#pragma unroll
    for(int h=0;h<8;h++) acc[h]=0.f;
#pragma unroll
    for(int e=0;e<8;e++){
      const float zn = (x[e]-mu)*rs*gz[e] + bz[e];
#pragma unroll
      for(int h=0;h<8;h++) acc[h] += zn*wb_r[e*8+h];
    }
    float k1[4];
    {
      const bool hi = lg & 1;
#pragma unroll
      for(int j=0;j<4;j++){
        float send = hi ? acc[j] : acc[j+4];
        float recv = __shfl_xor(send, 1, 64);
        k1[j] = (hi ? acc[j+4] : acc[j]) + recv;
      }
    }
    float k2[2];
    {
      const bool hi = lg & 2;
#pragma unroll
      for(int j=0;j<2;j++){
        float send = hi ? k1[j] : k1[j+2];
        float recv = __shfl_xor(send, 2, 64);
        k2[j] = (hi ? k1[j+2] : k1[j]) + recv;
      }
    }
    float k3;
    {
      const bool hi = lg & 4;
      float send = hi ? k2[0] : k2[1];
      float recv = __shfl_xor(send, 4, 64);
      k3 = (hi ? k2[1] : k2[0]) + recv;
    }
    k3 += __shfl_xor(k3, 8, 64);
    if(lg < 8) bias[(size_t)hmap*LL + r] = k3;
  }
}

/* ---- 3. s @ {Wq,Wk,Wv,Wg}^T; q(*scale),k -> bf16 rows; v -> bf16 transposed; gate fp32 ---- */
__global__ __launch_bounds__(256) void k_qkvg(
    const float* __restrict__ s,
    const float* __restrict__ Wq, const float* __restrict__ Wk,
    const float* __restrict__ Wv, const float* __restrict__ Wg,
    const float* __restrict__ bg,
    u16* __restrict__ qb, u16* __restrict__ kb,
    u16* __restrict__ vT, float* __restrict__ gate){
  const int which = blockIdx.z;
  const float* W = (which==0)?Wq : (which==1)?Wk : (which==2)?Wv : Wg;
  __shared__ float As[16][65];
  __shared__ float Bs[16][65];
  const int t = threadIdx.x;
  const int m0 = blockIdx.x*64;
  const int n0 = blockIdx.y*64;
  const int tx = t & 15, ty = t >> 4;
  float acc[4][4] = {};
  for(int k0=0;k0<CS;k0+=16){
#pragma unroll
    for(int e=0;e<4;e++){
      int idx = t + e*256;
      int kk = idx & 15, mm = idx >> 4;
      As[kk][mm] = s[(m0+mm)*CS + k0 + kk];
      Bs[kk][mm] = W[(n0+mm)*CS + k0 + kk];
    }
    __syncthreads();
#pragma unroll
    for(int kk=0;kk<16;kk++){
      float a[4], bb[4];
#pragma unroll
      for(int rr=0;rr<4;rr++) a[rr]=As[kk][ty+16*rr];
#pragma unroll
      for(int cc=0;cc<4;cc++) bb[cc]=Bs[kk][tx+16*cc];
#pragma unroll
      for(int rr=0;rr<4;rr++)
#pragma unroll
        for(int cc=0;cc<4;cc++) acc[rr][cc] += a[rr]*bb[cc];
    }
    __syncthreads();
  }
#pragma unroll
  for(int rr=0;rr<4;rr++){
    int m = m0 + ty + 16*rr;
#pragma unroll
    for(int cc=0;cc<4;cc++){
      int n = n0 + tx + 16*cc;
      float val = acc[rr][cc];
      if(which==0)      qb[m*CS+n] = f2bf_s(val*QK_SCALE);
      else if(which==1) kb[m*CS+n] = f2bf_s(val);
      else if(which==2) vT[(size_t)n*LSEQ + m] = f2bf_s(val);
      else              gate[m*CS+n] = 1.f/(1.f + __expf(-(val + bg[n])));
    }
  }
}

/* ---------- 4. fused flash attention (bf16 frags via vector loads) ---------- */
__global__ __launch_bounds__(256) void k_flash(
    const u16* __restrict__ qb, const u16* __restrict__ kb,
    const u16* __restrict__ vT, const float* __restrict__ bias,
    float* __restrict__ attno){
  const int h  = blockIdx.y;
  const int i0 = blockIdx.x * 16;
  const int t  = threadIdx.x;
  const int w    = t >> 6;
  const int lane = t & 63;
  const int ln   = lane & 15;
  const int quad = lane >> 4;

  __shared__ u16  S_lds[4][16][32];
  __shared__ float O_lds[4][16][48];
  __shared__ float ml_lds[4][2][16];

  const bf16x8 zf = {0,0,0,0,0,0,0,0};

  /* Q A-frags (QK_SCALE pre-folded): A[m=ln][k=quad*8+e] */
  bf16x8 aq0, aq1;
  {
    const u16* qrow = qb + (size_t)(i0 + ln)*CS + h*HD;
    aq0 = *(const bf16x8*)(qrow + quad*8);
    aq1 = (quad < 2) ? *(const bf16x8*)(qrow + 32 + quad*8) : zf;
  }

  float m_r[4], l_r[4];
  f32x4 o[3];
#pragma unroll
  for(int r=0;r<4;r++){ m_r[r] = -INFINITY; l_r[r] = 0.f; }
#pragma unroll
  for(int db=0;db<3;db++) o[db] = (f32x4){0.f,0.f,0.f,0.f};

  for(int jt=0; jt<6; jt++){
    const int j0 = w*192 + jt*32;
    f32x4 s_f[2];
#pragma unroll
    for(int jb=0;jb<2;jb++){
      const u16* krow = kb + (size_t)(j0 + jb*16 + ln)*CS + h*HD;
      bf16x8 bk0 = *(const bf16x8*)(krow + quad*8);
      bf16x8 bk1 = (quad < 2) ? *(const bf16x8*)(krow + 32 + quad*8) : zf;
      f32x4 acc = (f32x4){0.f,0.f,0.f,0.f};
      acc = __builtin_amdgcn_mfma_f32_16x16x32_bf16(aq0, bk0, acc, 0,0,0);
      acc = __builtin_amdgcn_mfma_f32_16x16x32_bf16(aq1, bk1, acc, 0,0,0);
      s_f[jb] = acc;
    }
    /* + bias; C-layout: row=quad*4+r, col=j0+jb*16+ln */
    float sv[2][4];
#pragma unroll
    for(int jb=0;jb<2;jb++)
#pragma unroll
      for(int r=0;r<4;r++)
        sv[jb][r] = s_f[jb][r] +
          bias[(size_t)h*LL + (size_t)(i0 + quad*4 + r)*LSEQ + j0 + jb*16 + ln];
    /* online softmax */
    float tmax[4];
#pragma unroll
    for(int r=0;r<4;r++) tmax[r] = fmaxf(sv[0][r], sv[1][r]);
#pragma unroll
    for(int r=0;r<4;r++)
#pragma unroll
      for(int m=1;m<16;m<<=1) tmax[r] = fmaxf(tmax[r], __shfl_xor(tmax[r], m, 64));
    float alpha[4];
#pragma unroll
    for(int r=0;r<4;r++){
      const float mn = fmaxf(m_r[r], tmax[r]);
      alpha[r] = __expf(m_r[r] - mn);
      m_r[r] = mn;
    }
    float p[2][4], tsum[4];
#pragma unroll
    for(int r=0;r<4;r++){
      p[0][r] = __expf(sv[0][r] - m_r[r]);
      p[1][r] = __expf(sv[1][r] - m_r[r]);
      tsum[r] = p[0][r] + p[1][r];
    }
#pragma unroll
    for(int r=0;r<4;r++)
#pragma unroll
      for(int m=1;m<16;m<<=1) tsum[r] += __shfl_xor(tsum[r], m, 64);
#pragma unroll
    for(int r=0;r<4;r++) l_r[r] = l_r[r]*alpha[r] + tsum[r];
#pragma unroll
    for(int db=0;db<3;db++)
#pragma unroll
      for(int r=0;r<4;r++) o[db][r] *= alpha[r];
    /* P: C-layout -> LDS(bf16) -> A-layout; intra-wave, no barrier needed */
#pragma unroll
    for(int jb=0;jb<2;jb++)
#pragma unroll
      for(int r=0;r<4;r++) S_lds[w][quad*4+r][jb*16+ln] = f2bf_s(p[jb][r]);
    bf16x8 ap = *(const bf16x8*)&S_lds[w][ln][quad*8];
    /* V B-frags from vT[h*48+d][j]: one 16-B load per db */
#pragma unroll
    for(int db=0;db<3;db++){
      bf16x8 bv = *(const bf16x8*)(vT + (size_t)(h*HD + db*16 + ln)*LSEQ + j0 + quad*8);
      o[db] = __builtin_amdgcn_mfma_f32_16x16x32_bf16(ap, bv, o[db], 0,0,0);
    }
  }

  /* merge the 4 j-quarters */
#pragma unroll
  for(int db=0;db<3;db++)
#pragma unroll
    for(int r=0;r<4;r++) O_lds[w][quad*4+r][db*16+ln] = o[db][r];
  if(ln == 0){
#pragma unroll
    for(int r=0;r<4;r++){
      ml_lds[w][0][quad*4+r] = m_r[r];
      ml_lds[w][1][quad*4+r] = l_r[r];
    }
  }
  __syncthreads();
#pragma unroll
  for(int e=0;e<3;e++){
    const int idx = t + e*256;
    const int row = idx / 48, d = idx % 48;
    float M = ml_lds[0][0][row];
#pragma unroll
    for(int ww=1;ww<4;ww++) M = fmaxf(M, ml_lds[ww][0][row]);
    float L = 0.f, O = 0.f;
#pragma unroll
    for(int ww=0;ww<4;ww++){
      const float f = __expf(ml_lds[ww][0][row] - M);
      L += ml_lds[ww][1][row] * f;
      O += O_lds[ww][row][d] * f;
    }
    attno[(size_t)(i0+row)*CS + h*HD + d] = O / L;
  }
}

/* ------- 5. out = single + gate * (attno @ Wo^T + bo), fp32 store ------- */
__global__ __launch_bounds__(256) void k_final(
    const float* __restrict__ attno, const float* __restrict__ Wo,
    const float* __restrict__ bo, const float* __restrict__ single,
    const float* __restrict__ gate, float* __restrict__ out){
  __shared__ float As[16][65];
  __shared__ float Bs[16][65];
  const int t = threadIdx.x;
  const int m0 = blockIdx.x*64;
  const int n0 = blockIdx.y*64;
  const int tx = t & 15, ty = t >> 4;
  float acc[4][4] = {};
  for(int k0=0;k0<CS;k0+=16){
#pragma unroll
    for(int e=0;e<4;e++){
      int idx = t + e*256;
      int kk = idx & 15, mm = idx >> 4;
      As[kk][mm] = attno[(m0+mm)*CS + k0 + kk];
      Bs[kk][mm] = Wo[(n0+mm)*CS + k0 + kk];
    }
    __syncthreads();
#pragma unroll
    for(int kk=0;kk<16;kk++){
      float a[4], bb[4];
#pragma unroll
      for(int rr=0;rr<4;rr++) a[rr]=As[kk][ty+16*rr];
#pragma unroll
      for(int cc=0;cc<4;cc++) bb[cc]=Bs[kk][tx+16*cc];
#pragma unroll
      for(int rr=0;rr<4;rr++)
#pragma unroll
        for(int cc=0;cc<4;cc++) acc[rr][cc] += a[rr]*bb[cc];
    }
    __syncthreads();
  }
#pragma unroll
  for(int rr=0;rr<4;rr++){
    int m = m0 + ty + 16*rr;
#pragma unroll
    for(int cc=0;cc<4;cc++){
      int n = n0 + tx + 16*cc;
      float val = acc[rr][cc] + bo[n];
      out[m*CS+n] = single[m*CS+n] + gate[m*CS+n]*val;
    }
  }
}

extern "C" void kernel_launch(void* const* d_in, const int* in_sizes, int n_in,
                              void* d_out, int out_size, void* d_ws, size_t ws_size,
                              hipStream_t stream){
  (void)in_sizes; (void)n_in; (void)out_size; (void)ws_size;
  const float* single = (const float*)d_in[0];
  const float* pair   = (const float*)d_in[1];
  const float* g_s    = (const float*)d_in[2];
  const float* b_s    = (const float*)d_in[3];
  const float* g_z    = (const float*)d_in[4];
  const float* b_z    = (const float*)d_in[5];
  const float* Wq     = (const float*)d_in[6];
  const float* Wk     = (const float*)d_in[7];
  const float* Wv     = (const float*)d_in[8];
  const float* Wb     = (const float*)d_in[9];
  const float* Wo     = (const float*)d_in[10];
  const float* bo     = (const float*)d_in[11];
  const float* Wg     = (const float*)d_in[12];
  const float* bg     = (const float*)d_in[13];
  float* out = (float*)d_out;

  float* ws     = (float*)d_ws;
  float* bias   = ws;                      /* [8][768][768] f32          */
  float* s      = ws + 4718592;            /* [768][384] f32             */
  float* gate   = s + 294912;              /* [768][384] f32             */
  float* attno  = gate + 294912;           /* [768][384] f32             */
  u16*   qb     = (u16*)(ws + 4718592 + 3*294912);  /* [768][384] bf16   */
  u16*   kb     = qb + 294912;             /* [768][384] bf16            */
  u16*   vT     = kb + 294912;             /* [384][768] bf16            */

  hipLaunchKernelGGL(k_ln_single, dim3(768),     dim3(64),  0, stream, single, g_s, b_s, s);
  hipLaunchKernelGGL(k_pair_bias, dim3(3072),    dim3(256), 0, stream, pair, g_z, b_z, Wb, bias);
  hipLaunchKernelGGL(k_qkvg,      dim3(12,6,4),  dim3(256), 0, stream, s, Wq, Wk, Wv, Wg, bg, qb, kb, vT, gate);
  hipLaunchKernelGGL(k_flash,     dim3(48,8),    dim3(256), 0, stream, qb, kb, vT, bias, attno);
  hipLaunchKernelGGL(k_final,     dim3(12,6),    dim3(256), 0, stream, attno, Wo, bo, single, gate, out);
}

// Round 5
// 488.369 us; speedup vs baseline: 1.1973x; 1.0656x over previous
//
#include <hip/hip_runtime.h>
#include <hip/hip_bf16.h>
#include <cstdint>
#include <cstddef>

#define LSEQ 768
#define CS 384
#define CZ 128
#define NH 8
#define HD 48
#define LL (LSEQ*LSEQ)   /* 589824 */
#define WELEM 147456     /* 384*384 */

static constexpr float EPS = 1e-5f;
static constexpr float QK_SCALE = 0.14433756729740643f; /* 1/sqrt(48) */

typedef unsigned short u16;
typedef __attribute__((ext_vector_type(8))) short bf16x8;
typedef __attribute__((ext_vector_type(4))) float f32x4;

__device__ __forceinline__ u16 f2bf_s(float f){
  unsigned int u = __float_as_uint(f);
  unsigned int r = u + 0x7fffu + ((u >> 16) & 1u);  /* RNE */
  return (u16)(r >> 16);
}

/* ------- 1. prep: blocks 0..191 = LayerNorm(single)->s_bf (4 rows/block);
             blocks 192..911 = cast {Wq,Wk,Wv,Wg,Wo} fp32->bf16 ------- */
__global__ __launch_bounds__(256) void k_prep(
    const float* __restrict__ single,
    const float* __restrict__ g, const float* __restrict__ b,
    const float* __restrict__ Wq, const float* __restrict__ Wk,
    const float* __restrict__ Wv, const float* __restrict__ Wg,
    const float* __restrict__ Wo,
    u16* __restrict__ s_bf, u16* __restrict__ Wbf){
  const int blk = blockIdx.x;
  if(blk < 192){
    const int wave = threadIdx.x >> 6, lane = threadIdx.x & 63;
    const int i = blk*4 + wave;
    const float* row = single + i*CS;
    float x[6];
    float sum = 0.f;
#pragma unroll
    for(int e=0;e<6;e++){ x[e] = row[lane + 64*e]; sum += x[e]; }
#pragma unroll
    for(int m=32;m>=1;m>>=1) sum += __shfl_xor(sum, m, 64);
    const float mu = sum * (1.f/CS);
    float vs = 0.f;
#pragma unroll
    for(int e=0;e<6;e++){ float d = x[e]-mu; vs += d*d; }
#pragma unroll
    for(int m=32;m>=1;m>>=1) vs += __shfl_xor(vs, m, 64);
    const float rs = rsqrtf(vs*(1.f/CS) + EPS);
#pragma unroll
    for(int e=0;e<6;e++){
      int c = lane + 64*e;
      s_bf[i*CS + c] = f2bf_s((x[e]-mu)*rs*g[c] + b[c]);
    }
  } else {
    const int idx = (blk-192)*256 + threadIdx.x;    /* float4 index, <184320 */
    const int which = idx / 36864;
    const int off = (idx - which*36864)*4;
    const float* src = (which==0)?Wq:(which==1)?Wk:(which==2)?Wv:(which==3)?Wg:Wo;
    const float4 u = *(const float4*)(src + off);
    ushort4 o;
    o.x = f2bf_s(u.x); o.y = f2bf_s(u.y); o.z = f2bf_s(u.z); o.w = f2bf_s(u.w);
    *(ushort4*)(Wbf + (size_t)which*WELEM + off) = o;
  }
}

/* ------- 2. fused LayerNorm(pair) + z@Wb -> bias[h][i][j] ------- */
__global__ __launch_bounds__(256,4) void k_pair_bias(
    const float* __restrict__ pair,
    const float* __restrict__ g_z,
    const float* __restrict__ b_z,
    const float* __restrict__ Wb,
    float* __restrict__ bias){
  const int t = threadIdx.x;
  const int lane = t & 63;
  const int wave = t >> 6;
  const int sub  = lane >> 4;
  const int lg   = lane & 15;
  const int z0   = lg*8;

  float wb_r[64], gz[8], bz[8];
#pragma unroll
  for(int zz=0; zz<8; zz++){
    gz[zz] = g_z[z0+zz];
    bz[zz] = b_z[z0+zz];
#pragma unroll
    for(int h=0; h<NH; h++) wb_r[zz*8+h] = Wb[(z0+zz)*NH + h];
  }
  const int hmap = 4*(lg&1) + (lg&2) + ((lg>>2)&1);

  const int ngroups = LL/16;
  for(int gidx = blockIdx.x; gidx < ngroups; gidx += gridDim.x){
    const int r = gidx*16 + wave*4 + sub;
    const float4 u0 = *(const float4*)(pair + (size_t)r*CZ + z0);
    const float4 u1 = *(const float4*)(pair + (size_t)r*CZ + z0 + 4);
    float x[8] = {u0.x,u0.y,u0.z,u0.w,u1.x,u1.y,u1.z,u1.w};
    float sum=0.f, sq=0.f;
#pragma unroll
    for(int e=0;e<8;e++){ sum += x[e]; sq += x[e]*x[e]; }
#pragma unroll
    for(int m=1;m<16;m<<=1){ sum += __shfl_xor(sum,m,64); sq += __shfl_xor(sq,m,64); }
    const float mu = sum*(1.f/CZ);
    const float rs = rsqrtf(sq*(1.f/CZ) - mu*mu + EPS);
    float acc[8];
#pragma unroll
    for(int h=0;h<8;h++) acc[h]=0.f;
#pragma unroll
    for(int e=0;e<8;e++){
      const float zn = (x[e]-mu)*rs*gz[e] + bz[e];
#pragma unroll
      for(int h=0;h<8;h++) acc[h] += zn*wb_r[e*8+h];
    }
    float k1[4];
    {
      const bool hi = lg & 1;
#pragma unroll
      for(int j=0;j<4;j++){
        float send = hi ? acc[j] : acc[j+4];
        float recv = __shfl_xor(send, 1, 64);
        k1[j] = (hi ? acc[j+4] : acc[j]) + recv;
      }
    }
    float k2[2];
    {
      const bool hi = lg & 2;
#pragma unroll
      for(int j=0;j<2;j++){
        float send = hi ? k1[j] : k1[j+2];
        float recv = __shfl_xor(send, 2, 64);
        k2[j] = (hi ? k1[j+2] : k1[j]) + recv;
      }
    }
    float k3;
    {
      const bool hi = lg & 4;
      float send = hi ? k2[0] : k2[1];
      float recv = __shfl_xor(send, 4, 64);
      k3 = (hi ? k2[1] : k2[0]) + recv;
    }
    k3 += __shfl_xor(k3, 8, 64);
    if(lg < 8) bias[(size_t)hmap*LL + r] = k3;
  }
}

/* ---- 3. MFMA GEMM: s_bf @ {Wq,Wk,Wv,Wg}^T, direct-from-global frags ----
   Block 256 = 4 waves; tile 64(M)x64(N); wave w rows m0+w*16. K=384.     */
__global__ __launch_bounds__(256) void k_qkvg(
    const u16* __restrict__ s_bf, const u16* __restrict__ Wbf,
    const float* __restrict__ bg,
    u16* __restrict__ qb, u16* __restrict__ kb,
    u16* __restrict__ vT, float* __restrict__ gate){
  const int t = threadIdx.x;
  const int w = t >> 6, lane = t & 63, ln = lane & 15, quad = lane >> 4;
  const int m0 = blockIdx.x*64 + w*16;
  const int which = blockIdx.y / 6;
  const int n0 = (blockIdx.y % 6)*64;
  const u16* W = Wbf + (size_t)which*WELEM;

  const u16* arow = s_bf + (size_t)(m0+ln)*CS + quad*8;
  const u16* brow = W + (size_t)(n0+ln)*CS + quad*8;

  f32x4 acc[4];
#pragma unroll
  for(int nb=0;nb<4;nb++) acc[nb] = (f32x4){0.f,0.f,0.f,0.f};

#pragma unroll 4
  for(int k0=0;k0<CS;k0+=32){
    bf16x8 a = *(const bf16x8*)(arow + k0);
#pragma unroll
    for(int nb=0;nb<4;nb++){
      bf16x8 bb = *(const bf16x8*)(brow + (size_t)nb*16*CS + k0);
      acc[nb] = __builtin_amdgcn_mfma_f32_16x16x32_bf16(a, bb, acc[nb], 0,0,0);
    }
  }

  if(which == 2){           /* v -> transposed bf16, 8B stores */
#pragma unroll
    for(int nb=0;nb<4;nb++){
      const int col = n0 + nb*16 + ln;
      ushort4 sv;
      sv.x = f2bf_s(acc[nb][0]); sv.y = f2bf_s(acc[nb][1]);
      sv.z = f2bf_s(acc[nb][2]); sv.w = f2bf_s(acc[nb][3]);
      *(ushort4*)(vT + (size_t)col*LSEQ + m0 + quad*4) = sv;
    }
  } else {
#pragma unroll
    for(int nb=0;nb<4;nb++){
#pragma unroll
      for(int r=0;r<4;r++){
        const int row = m0 + quad*4 + r;
        const int col = n0 + nb*16 + ln;
        const float val = acc[nb][r];
        if(which==0)      qb[row*CS+col] = f2bf_s(val*QK_SCALE);
        else if(which==1) kb[row*CS+col] = f2bf_s(val);
        else              gate[row*CS+col] = 1.f/(1.f + __expf(-(val + bg[col])));
      }
    }
  }
}

/* ---------- 4. fused flash attention (bf16 frags via vector loads) ---------- */
__global__ __launch_bounds__(256) void k_flash(
    const u16* __restrict__ qb, const u16* __restrict__ kb,
    const u16* __restrict__ vT, const float* __restrict__ bias,
    u16* __restrict__ attno_bf){
  const int h  = blockIdx.y;
  const int i0 = blockIdx.x * 16;
  const int t  = threadIdx.x;
  const int w    = t >> 6;
  const int lane = t & 63;
  const int ln   = lane & 15;
  const int quad = lane >> 4;

  __shared__ u16  S_lds[4][16][32];
  __shared__ float O_lds[4][16][48];
  __shared__ float ml_lds[4][2][16];

  const bf16x8 zf = {0,0,0,0,0,0,0,0};

  bf16x8 aq0, aq1;
  {
    const u16* qrow = qb + (size_t)(i0 + ln)*CS + h*HD;
    aq0 = *(const bf16x8*)(qrow + quad*8);
    aq1 = (quad < 2) ? *(const bf16x8*)(qrow + 32 + quad*8) : zf;
  }

  float m_r[4], l_r[4];
  f32x4 o[3];
#pragma unroll
  for(int r=0;r<4;r++){ m_r[r] = -INFINITY; l_r[r] = 0.f; }
#pragma unroll
  for(int db=0;db<3;db++) o[db] = (f32x4){0.f,0.f,0.f,0.f};

  for(int jt=0; jt<6; jt++){
    const int j0 = w*192 + jt*32;
    f32x4 s_f[2];
#pragma unroll
    for(int jb=0;jb<2;jb++){
      const u16* krow = kb + (size_t)(j0 + jb*16 + ln)*CS + h*HD;
      bf16x8 bk0 = *(const bf16x8*)(krow + quad*8);
      bf16x8 bk1 = (quad < 2) ? *(const bf16x8*)(krow + 32 + quad*8) : zf;
      f32x4 acc = (f32x4){0.f,0.f,0.f,0.f};
      acc = __builtin_amdgcn_mfma_f32_16x16x32_bf16(aq0, bk0, acc, 0,0,0);
      acc = __builtin_amdgcn_mfma_f32_16x16x32_bf16(aq1, bk1, acc, 0,0,0);
      s_f[jb] = acc;
    }
    float sv[2][4];
#pragma unroll
    for(int jb=0;jb<2;jb++)
#pragma unroll
      for(int r=0;r<4;r++)
        sv[jb][r] = s_f[jb][r] +
          bias[(size_t)h*LL + (size_t)(i0 + quad*4 + r)*LSEQ + j0 + jb*16 + ln];
    float tmax[4];
#pragma unroll
    for(int r=0;r<4;r++) tmax[r] = fmaxf(sv[0][r], sv[1][r]);
#pragma unroll
    for(int r=0;r<4;r++)
#pragma unroll
      for(int m=1;m<16;m<<=1) tmax[r] = fmaxf(tmax[r], __shfl_xor(tmax[r], m, 64));
    float alpha[4];
#pragma unroll
    for(int r=0;r<4;r++){
      const float mn = fmaxf(m_r[r], tmax[r]);
      alpha[r] = __expf(m_r[r] - mn);
      m_r[r] = mn;
    }
    float p[2][4], tsum[4];
#pragma unroll
    for(int r=0;r<4;r++){
      p[0][r] = __expf(sv[0][r] - m_r[r]);
      p[1][r] = __expf(sv[1][r] - m_r[r]);
      tsum[r] = p[0][r] + p[1][r];
    }
#pragma unroll
    for(int r=0;r<4;r++)
#pragma unroll
      for(int m=1;m<16;m<<=1) tsum[r] += __shfl_xor(tsum[r], m, 64);
#pragma unroll
    for(int r=0;r<4;r++) l_r[r] = l_r[r]*alpha[r] + tsum[r];
#pragma unroll
    for(int db=0;db<3;db++)
#pragma unroll
      for(int r=0;r<4;r++) o[db][r] *= alpha[r];
#pragma unroll
    for(int jb=0;jb<2;jb++)
#pragma unroll
      for(int r=0;r<4;r++) S_lds[w][quad*4+r][jb*16+ln] = f2bf_s(p[jb][r]);
    bf16x8 ap = *(const bf16x8*)&S_lds[w][ln][quad*8];
#pragma unroll
    for(int db=0;db<3;db++){
      bf16x8 bv = *(const bf16x8*)(vT + (size_t)(h*HD + db*16 + ln)*LSEQ + j0 + quad*8);
      o[db] = __builtin_amdgcn_mfma_f32_16x16x32_bf16(ap, bv, o[db], 0,0,0);
    }
  }

#pragma unroll
  for(int db=0;db<3;db++)
#pragma unroll
    for(int r=0;r<4;r++) O_lds[w][quad*4+r][db*16+ln] = o[db][r];
  if(ln == 0){
#pragma unroll
    for(int r=0;r<4;r++){
      ml_lds[w][0][quad*4+r] = m_r[r];
      ml_lds[w][1][quad*4+r] = l_r[r];
    }
  }
  __syncthreads();
#pragma unroll
  for(int e=0;e<3;e++){
    const int idx = t + e*256;
    const int row = idx / 48, d = idx % 48;
    float M = ml_lds[0][0][row];
#pragma unroll
    for(int ww=1;ww<4;ww++) M = fmaxf(M, ml_lds[ww][0][row]);
    float L = 0.f, O = 0.f;
#pragma unroll
    for(int ww=0;ww<4;ww++){
      const float f = __expf(ml_lds[ww][0][row] - M);
      L += ml_lds[ww][1][row] * f;
      O += O_lds[ww][row][d] * f;
    }
    attno_bf[(size_t)(i0+row)*CS + h*HD + d] = f2bf_s(O / L);
  }
}

/* ---- 5. MFMA GEMM: out = single + gate * (attno_bf @ Wo^T + bo) ---- */
__global__ __launch_bounds__(256) void k_final(
    const u16* __restrict__ attno_bf, const u16* __restrict__ Wo_bf,
    const float* __restrict__ bo, const float* __restrict__ single,
    const float* __restrict__ gate, float* __restrict__ out){
  const int t = threadIdx.x;
  const int w = t >> 6, lane = t & 63, ln = lane & 15, quad = lane >> 4;
  const int m0 = blockIdx.x*64 + w*16;
  const int n0 = blockIdx.y*64;

  const u16* arow = attno_bf + (size_t)(m0+ln)*CS + quad*8;
  const u16* brow = Wo_bf + (size_t)(n0+ln)*CS + quad*8;

  f32x4 acc[4];
#pragma unroll
  for(int nb=0;nb<4;nb++) acc[nb] = (f32x4){0.f,0.f,0.f,0.f};

#pragma unroll 4
  for(int k0=0;k0<CS;k0+=32){
    bf16x8 a = *(const bf16x8*)(arow + k0);
#pragma unroll
    for(int nb=0;nb<4;nb++){
      bf16x8 bb = *(const bf16x8*)(brow + (size_t)nb*16*CS + k0);
      acc[nb] = __builtin_amdgcn_mfma_f32_16x16x32_bf16(a, bb, acc[nb], 0,0,0);
    }
  }
#pragma unroll
  for(int nb=0;nb<4;nb++){
#pragma unroll
    for(int r=0;r<4;r++){
      const int row = m0 + quad*4 + r;
      const int col = n0 + nb*16 + ln;
      const float val = acc[nb][r] + bo[col];
      out[row*CS+col] = single[row*CS+col] + gate[row*CS+col]*val;
    }
  }
}

extern "C" void kernel_launch(void* const* d_in, const int* in_sizes, int n_in,
                              void* d_out, int out_size, void* d_ws, size_t ws_size,
                              hipStream_t stream){
  (void)in_sizes; (void)n_in; (void)out_size; (void)ws_size;
  const float* single = (const float*)d_in[0];
  const float* pair   = (const float*)d_in[1];
  const float* g_s    = (const float*)d_in[2];
  const float* b_s    = (const float*)d_in[3];
  const float* g_z    = (const float*)d_in[4];
  const float* b_z    = (const float*)d_in[5];
  const float* Wq     = (const float*)d_in[6];
  const float* Wk     = (const float*)d_in[7];
  const float* Wv     = (const float*)d_in[8];
  const float* Wb     = (const float*)d_in[9];
  const float* Wo     = (const float*)d_in[10];
  const float* bo     = (const float*)d_in[11];
  const float* Wg     = (const float*)d_in[12];
  const float* bg     = (const float*)d_in[13];
  float* out = (float*)d_out;

  float* ws     = (float*)d_ws;
  float* bias   = ws;                       /* [8][768][768] f32 */
  float* gate   = ws + 4718592;             /* [768][384] f32    */
  u16*   s_bf   = (u16*)(gate + 294912);    /* [768][384] bf16   */
  u16*   qb     = s_bf + 294912;            /* [768][384] bf16   */
  u16*   kb     = qb + 294912;              /* [768][384] bf16   */
  u16*   vT     = kb + 294912;              /* [384][768] bf16   */
  u16*   attno  = vT + 294912;              /* [768][384] bf16   */
  u16*   Wbf    = attno + 294912;           /* 5*[384][384] bf16 */

  hipLaunchKernelGGL(k_prep,      dim3(912),    dim3(256), 0, stream,
                     single, g_s, b_s, Wq, Wk, Wv, Wg, Wo, s_bf, Wbf);
  hipLaunchKernelGGL(k_pair_bias, dim3(3072),   dim3(256), 0, stream, pair, g_z, b_z, Wb, bias);
  hipLaunchKernelGGL(k_qkvg,      dim3(12,24),  dim3(256), 0, stream,
                     s_bf, Wbf, bg, qb, kb, vT, gate);
  hipLaunchKernelGGL(k_flash,     dim3(48,8),   dim3(256), 0, stream, qb, kb, vT, bias, attno);
  hipLaunchKernelGGL(k_final,     dim3(12,6),   dim3(256), 0, stream,
                     attno, Wbf + (size_t)4*WELEM, bo, single, gate, out);
}